// Round 6
// baseline (367.630 us; speedup 1.0000x reference)
//
#include <hip/hip_runtime.h>
#include <math.h>

#define DD 64
typedef float v4f __attribute__((ext_vector_type(4)));

// ---------------------------------------------------------------------------
// prep: row_start[v] = lower_bound(dst, v) for v in [0,N], row_start[N]=E
// ---------------------------------------------------------------------------
__global__ void prep_kernel(const int* __restrict__ dst,
                            int* __restrict__ row_start,
                            int N, int E) {
    int t = blockIdx.x * blockDim.x + threadIdx.x;
    if (t <= N) {
        if (t == N) {
            row_start[N] = E;
        } else {
            int lo = 0, hi = E;
            while (lo < hi) {
                int mid = (lo + hi) >> 1;
                if (dst[mid] < t) lo = mid + 1; else hi = mid;
            }
            row_start[t] = lo;
        }
    }
}

// ---------------------------------------------------------------------------
// DIAGNOSTIC ROUND: the edge loop runs TWICE (pass 2 into se2/sm2, kept
// live by a never-true uniform store guard, lane mapping grp^3 to defeat
// load CSE/loop fusion). Purpose: double agg's duration above the 122 us
// harness fills so its hbm_gbps / VALUBusy / Occupancy / FETCH_SIZE become
// visible in the top-5 for the first time. Output is bit-identical to R5.
// ---------------------------------------------------------------------------
__global__ __launch_bounds__(256) void agg_kernel(
    const float* __restrict__ node_feats,
    const float* __restrict__ edge_feats,
    const int*   __restrict__ src,
    const int*   __restrict__ row_start,
    float*       __restrict__ agg,
    int N)
{
    const int wave = threadIdx.x >> 6;
    const int lane = threadIdx.x & 63;
    const int grp  = lane >> 4;     // edge slot 0..3
    const int qd   = lane & 15;     // dim quad: dims 4qd..4qd+3
    const int v = blockIdx.x * 4 + wave;
    if (v >= N) return;

    const int e0 = row_start[v];
    const int e1 = row_start[v + 1];
    const int rsN = row_start[N];   // == E (>0); guard for the dead store

    const v4f* __restrict__ nf4 = (const v4f*)node_feats;
    const v4f* __restrict__ ef4 = (const v4f*)edge_feats;

    // ---------------- pass 1 (real) ----------------
    v4f se = {0.f, 0.f, 0.f, 0.f};
    v4f sm = {0.f, 0.f, 0.f, 0.f};
    for (int eb = e0; eb < e1; eb += 8) {
        const int ea  = eb + grp;
        const int eb2 = eb + 4 + grp;
        const bool va = ea  < e1;
        const bool vb = eb2 < e1;
        const int eca = va ? ea  : e0;
        const int ecb = vb ? eb2 : e0;
        const int sa = src[eca];
        const int sb = src[ecb];
        const v4f ga = __builtin_nontemporal_load(ef4 + (size_t)eca * 16 + qd);
        const v4f gb = __builtin_nontemporal_load(ef4 + (size_t)ecb * 16 + qd);
        const v4f na = nf4[(size_t)sa * 16 + qd];
        const v4f nb = nf4[(size_t)sb * 16 + qd];
        const v4f ma = na + ga;
        const v4f mb = nb + gb;
        v4f xa, xb;
        xa.x = va ? __expf(ma.x) : 0.f;
        xa.y = va ? __expf(ma.y) : 0.f;
        xa.z = va ? __expf(ma.z) : 0.f;
        xa.w = va ? __expf(ma.w) : 0.f;
        xb.x = vb ? __expf(mb.x) : 0.f;
        xb.y = vb ? __expf(mb.y) : 0.f;
        xb.z = vb ? __expf(mb.z) : 0.f;
        xb.w = vb ? __expf(mb.w) : 0.f;
        se += xa;  se += xb;
        sm += ma * xa;  sm += mb * xb;
    }

    // ---------------- pass 2 (timing replica; result dead at runtime) ------
    const int grp2 = grp ^ 3;   // different lane->edge map, same edge set
    v4f se2 = {0.f, 0.f, 0.f, 0.f};
    v4f sm2 = {0.f, 0.f, 0.f, 0.f};
    for (int eb = e0; eb < e1; eb += 8) {
        const int ea  = eb + grp2;
        const int eb2 = eb + 4 + grp2;
        const bool va = ea  < e1;
        const bool vb = eb2 < e1;
        const int eca = va ? ea  : e0;
        const int ecb = vb ? eb2 : e0;
        const int sa = src[eca];
        const int sb = src[ecb];
        const v4f ga = __builtin_nontemporal_load(ef4 + (size_t)eca * 16 + qd);
        const v4f gb = __builtin_nontemporal_load(ef4 + (size_t)ecb * 16 + qd);
        const v4f na = nf4[(size_t)sa * 16 + qd];
        const v4f nb = nf4[(size_t)sb * 16 + qd];
        const v4f ma = na + ga;
        const v4f mb = nb + gb;
        v4f xa, xb;
        xa.x = va ? __expf(ma.x) : 0.f;
        xa.y = va ? __expf(ma.y) : 0.f;
        xa.z = va ? __expf(ma.z) : 0.f;
        xa.w = va ? __expf(ma.w) : 0.f;
        xb.x = vb ? __expf(mb.x) : 0.f;
        xb.y = vb ? __expf(mb.y) : 0.f;
        xb.z = vb ? __expf(mb.z) : 0.f;
        xb.w = vb ? __expf(mb.w) : 0.f;
        se2 += xa;  se2 += xb;
        sm2 += ma * xa;  sm2 += mb * xb;
    }
    if (rsN < 0) {   // never true (rsN == E > 0); compiler can't prove it
        agg[(size_t)v * DD + lane] = se2.x + se2.y + se2.z + se2.w
                                   + sm2.x + sm2.y + sm2.z + sm2.w;
        return;
    }

    // butterfly over the 4 edge slots (lane bits 4,5) — pass 1 only
    for (int off = 16; off < 64; off <<= 1) {
        se.x += __shfl_xor(se.x, off, 64);
        se.y += __shfl_xor(se.y, off, 64);
        se.z += __shfl_xor(se.z, off, 64);
        se.w += __shfl_xor(se.w, off, 64);
        sm.x += __shfl_xor(sm.x, off, 64);
        sm.y += __shfl_xor(sm.y, off, 64);
        sm.z += __shfl_xor(sm.z, off, 64);
        sm.w += __shfl_xor(sm.w, off, 64);
    }

    if (grp == 0) {
        v4f a;
        a.x = sm.x / fmaxf(se.x, 1e-38f);
        a.y = sm.y / fmaxf(se.y, 1e-38f);
        a.z = sm.z / fmaxf(se.z, 1e-38f);
        a.w = sm.w / fmaxf(se.w, 1e-38f);
        ((v4f*)agg)[(size_t)v * 16 + qd] = a;
    }
}

// ---------------------------------------------------------------------------
// phase 2: out = relu(agg @ W^T + b) + node_feats.  (unchanged from R5)
// ---------------------------------------------------------------------------
__global__ __launch_bounds__(256) void mlp_kernel(
    const float* __restrict__ agg,
    const float* __restrict__ node_feats,
    const float* __restrict__ W,       // [64,64] row-major: W[j][d]
    const float* __restrict__ bvec,
    float*       __restrict__ out,
    int N)
{
    const int lane = threadIdx.x & 63;   // output dim j
    const int wave = threadIdx.x >> 6;

    v4f wreg[16];
#pragma unroll
    for (int q = 0; q < 16; ++q)
        wreg[q] = ((const v4f*)W)[(size_t)lane * 16 + q];
    const float bj = bvec[lane];

    const int v0    = blockIdx.x * 64 + wave * 16;
    const int v_end = (v0 + 16 < N) ? (v0 + 16) : N;

    for (int v = v0; v < v_end; ++v) {
        const int vu = __builtin_amdgcn_readfirstlane(v);
        const v4f* __restrict__ arow = (const v4f*)(agg + (size_t)vu * DD);
        float acc = bj;
#pragma unroll
        for (int q = 0; q < 16; ++q) {
            const v4f a = arow[q];
            acc = fmaf(a.x, wreg[q].x, acc);
            acc = fmaf(a.y, wreg[q].y, acc);
            acc = fmaf(a.z, wreg[q].z, acc);
            acc = fmaf(a.w, wreg[q].w, acc);
        }
        const float res = node_feats[(size_t)vu * DD + lane];
        out[(size_t)vu * DD + lane] = fmaxf(acc, 0.f) + res;
    }
}

// ---------------------------------------------------------------------------
extern "C" void kernel_launch(void* const* d_in, const int* in_sizes, int n_in,
                              void* d_out, int out_size, void* d_ws, size_t ws_size,
                              hipStream_t stream) {
    const float* node_feats = (const float*)d_in[0];  // [N, 64]
    const float* edge_feats = (const float*)d_in[1];  // [E, 64]
    const int*   src        = (const int*)  d_in[2];  // [E]
    const int*   dst        = (const int*)  d_in[3];  // [E] sorted
    const float* W          = (const float*)d_in[4];  // [64, 64]
    const float* bvec       = (const float*)d_in[5];  // [64]
    float*       out        = (float*)d_out;

    const int N = in_sizes[0] / DD;
    const int E = in_sizes[2];

    // workspace: row_start[(N+1) ints] | pad to 256B | agg[N*64 floats]
    int*   row_start = (int*)d_ws;
    size_t agg_off = (((size_t)(N + 1) * sizeof(int)) + 255) & ~(size_t)255;
    float* agg = (float*)((char*)d_ws + agg_off);

    {
        int blocks = (N + 1 + 255) / 256;
        prep_kernel<<<blocks, 256, 0, stream>>>(dst, row_start, N, E);
    }
    {
        int blocks = (N + 3) / 4;
        agg_kernel<<<blocks, 256, 0, stream>>>(node_feats, edge_feats, src,
                                               row_start, agg, N);
    }
    {
        int blocks = (N + 63) / 64;
        mlp_kernel<<<blocks, 256, 0, stream>>>(agg, node_feats, W, bvec, out, N);
    }
}